// Round 8
// baseline (149.350 us; speedup 1.0000x reference)
//
#include <hip/hip_runtime.h>

#define B_  8
#define TQ  256
#define TV  512
#define DD  256

__device__ __forceinline__ float fast_exp2(float x) {
#if __has_builtin(__builtin_amdgcn_exp2f)
  return __builtin_amdgcn_exp2f(x);
#else
  return __exp2f(x);
#endif
}
__device__ __forceinline__ float fast_rcp(float x) {
#if __has_builtin(__builtin_amdgcn_rcpf)
  return __builtin_amdgcn_rcpf(x);
#else
  return 1.0f / x;
#endif
}

// ---------------------------------------------------------------------------
// Fused projections with EXP epilogue:
//   Eq = exp2(SC*(query@W1 + b1)),  Ev = exp2(SC*(value@W2 + b2))
// REWRITTEN: BM=64, BN=64, BK=32, 4x4 microtile, double-buffered LDS,
// one barrier per chunk, register prefetch of chunk c+1 during compute of c.
// As is stored transposed [k][m] with XOR swizzle sw(k)=((k>>2)&7)<<2 so both
// the scalar transpose-writes (32 distinct banks per 32-lane phase) and the
// b128 micro-reads (16-lane broadcast) are conflict-free with NO padding.
// Per k: 2 ds_read_b128 (24 cy) feed 16 FMA (32 cy) -> VALU-bound.
// Grid: 96 row-tiles (32 query + 64 value) x 4 col-tiles = 384 blocks.
// ---------------------------------------------------------------------------
__global__ __launch_bounds__(256) void proj_fused(
    const float* __restrict__ query, const float* __restrict__ value,
    const float* __restrict__ W1, const float* __restrict__ b1,
    const float* __restrict__ W2, const float* __restrict__ b2,
    float* __restrict__ qp, float* __restrict__ vp, float scale) {
  __shared__ float As[2][32][64];  // [p][k][m ^ sw(k)]
  __shared__ float Bs[2][32][64];  // [p][k][n]
  const int t  = threadIdx.x;
  const int rt = blockIdx.x;
  const int bn = blockIdx.y << 6;

  const float* A; const float* W; const float* bias; float* out; int row0;
  if (rt < 32) { row0 = rt << 6;        A = query; W = W1; bias = b1; out = qp; }
  else         { row0 = (rt - 32) << 6; A = value; W = W2; bias = b2; out = vp; }

  const int tx = t & 15, ty = t >> 4;
  const int aar = t >> 3, aac = (t & 7) << 2;   // A stage: row-in-half, k-col
  const int bbr = t >> 4, bbc = (t & 15) << 2;  // B stage: k-row-in-half, col

  float4 ra[2], rb[2];

  // chunk 0 loads
#pragma unroll
  for (int it = 0; it < 2; ++it) {
    ra[it] = *(const float4*)(A + (size_t)(row0 + (it << 5) + aar) * DD + aac);
    rb[it] = *(const float4*)(W + (size_t)((it << 4) + bbr) * DD + bn + bbc);
  }
#pragma unroll
  for (int it = 0; it < 2; ++it) {
    const int m = (it << 5) + aar;
#pragma unroll
    for (int c = 0; c < 4; ++c) {
      const int k = aac + c;
      As[0][k][m ^ (((k >> 2) & 7) << 2)] = (&ra[it].x)[c];
    }
    *(float4*)&Bs[0][(it << 4) + bbr][bbc] = rb[it];
  }
  __syncthreads();

  float acc[4][4] = {{0.f,0.f,0.f,0.f},{0.f,0.f,0.f,0.f},
                     {0.f,0.f,0.f,0.f},{0.f,0.f,0.f,0.f}};
  int p = 0;

  for (int k0 = 0; k0 < 256; k0 += 32) {
    const bool more = (k0 + 32) < 256;
    if (more) {
#pragma unroll
      for (int it = 0; it < 2; ++it) {
        ra[it] = *(const float4*)(A + (size_t)(row0 + (it << 5) + aar) * DD + k0 + 32 + aac);
        rb[it] = *(const float4*)(W + (size_t)(k0 + 32 + (it << 4) + bbr) * DD + bn + bbc);
      }
    }
#pragma unroll
    for (int k = 0; k < 32; ++k) {
      float4 aq = *(const float4*)&As[p][k][(ty << 2) ^ (((k >> 2) & 7) << 2)];
      float4 bq = *(const float4*)&Bs[p][k][tx << 2];
      acc[0][0] = fmaf(aq.x, bq.x, acc[0][0]); acc[0][1] = fmaf(aq.x, bq.y, acc[0][1]);
      acc[0][2] = fmaf(aq.x, bq.z, acc[0][2]); acc[0][3] = fmaf(aq.x, bq.w, acc[0][3]);
      acc[1][0] = fmaf(aq.y, bq.x, acc[1][0]); acc[1][1] = fmaf(aq.y, bq.y, acc[1][1]);
      acc[1][2] = fmaf(aq.y, bq.z, acc[1][2]); acc[1][3] = fmaf(aq.y, bq.w, acc[1][3]);
      acc[2][0] = fmaf(aq.z, bq.x, acc[2][0]); acc[2][1] = fmaf(aq.z, bq.y, acc[2][1]);
      acc[2][2] = fmaf(aq.z, bq.z, acc[2][2]); acc[2][3] = fmaf(aq.z, bq.w, acc[2][3]);
      acc[3][0] = fmaf(aq.w, bq.x, acc[3][0]); acc[3][1] = fmaf(aq.w, bq.y, acc[3][1]);
      acc[3][2] = fmaf(aq.w, bq.z, acc[3][2]); acc[3][3] = fmaf(aq.w, bq.w, acc[3][3]);
    }
    if (more) {
      const int q = p ^ 1;
#pragma unroll
      for (int it = 0; it < 2; ++it) {
        const int m = (it << 5) + aar;
#pragma unroll
        for (int c = 0; c < 4; ++c) {
          const int k = aac + c;
          As[q][k][m ^ (((k >> 2) & 7) << 2)] = (&ra[it].x)[c];
        }
        *(float4*)&Bs[q][(it << 4) + bbr][bbc] = rb[it];
      }
      __syncthreads();
      p = q;
    }
  }

  float4 bvv = *(const float4*)&bias[bn + (tx << 2)];
#pragma unroll
  for (int r = 0; r < 4; ++r) {
    float4 o;
    o.x = fast_exp2(scale * (acc[r][0] + bvv.x));
    o.y = fast_exp2(scale * (acc[r][1] + bvv.y));
    o.z = fast_exp2(scale * (acc[r][2] + bvv.z));
    o.w = fast_exp2(scale * (acc[r][3] + bvv.w));
    *(float4*)(out + (size_t)(row0 + (ty << 2) + r) * DD + bn + (tx << 2)) = o;
  }
}

// ---------------------------------------------------------------------------
// Fused score + softmax + context + concat + transposed alignment.
// (byte-identical to round 7 — validated, 70.5 µs)
// ---------------------------------------------------------------------------
__global__ __launch_bounds__(512, 4) void attn_kernel(
    const float* __restrict__ qp, const float* __restrict__ vp,
    const float* __restrict__ value, const float* __restrict__ query,
    float* __restrict__ out1, float* __restrict__ out2) {
  __shared__ float vs[512 * 36];  // 73728 B; aliased as alg[4][512] after loop
  float* alg = vs;                // alg[i*512 + j]

  const int t    = threadIdx.x;
  const int lane = t & 63;
  const int wv   = t >> 6;        // 0..7
  const int bb   = blockIdx.x & 7;          // batch -> XCD locality
  const int i0   = (blockIdx.x >> 3) << 2;  // first q-row of this block
  const int jrow = (wv << 6) + lane;        // this lane's j (fixed)

  const float* vpb = vp + (size_t)bb * TV * DD;
  const float* qb  = qp + (size_t)(bb * TQ + i0) * DD;  // wave-uniform reads

  const int j0   = t >> 3;        // staging: row within 64-row group
  const int col4 = (t & 7) << 2;  // staging: d-col (floats)

  float acc[4] = {0.f, 0.f, 0.f, 0.f};

#pragma unroll 1
  for (int dc = 0; dc < 8; ++dc) {
    const int dbase = dc << 5;  // 32 d's per chunk
#pragma unroll
    for (int k = 0; k < 8; ++k) {
      const int j = (k << 6) + j0;
      float4 x = *(const float4*)(vpb + (size_t)j * DD + dbase + col4);
      *(float4*)&vs[j * 36 + col4] = x;
    }
    __syncthreads();

#pragma unroll
    for (int d4 = 0; d4 < 8; ++d4) {
      float4 v4 = *(const float4*)&vs[jrow * 36 + (d4 << 2)];
#pragma unroll
      for (int i = 0; i < 4; ++i) {
        float4 q4 = *(const float4*)(qb + i * DD + dbase + (d4 << 2));
        float a = q4.x * v4.x, b = q4.y * v4.y;
        float c = q4.z * v4.z, d = q4.w * v4.w;
        float sab = a + b,  scd = c + d;
        float Q1 = fmaf(a, b, sab + 1.f);   // (1+a)(1+b)
        float Q2 = fmaf(c, d, scd + 1.f);   // (1+c)(1+d)
        float P1 = sab + 2.f, P2 = scd + 2.f;
        float N  = fmaf(P2, Q1, P1 * Q2);
        acc[i] = fmaf(N, fast_rcp(Q1 * Q2), acc[i]);
      }
    }
    __syncthreads();  // all v-reads done before next stage overwrites
  }

  // ---- scores -> alg (aliases vs; all chunk reads already fenced) ----
#pragma unroll
  for (int i = 0; i < 4; ++i) alg[(i << 9) + jrow] = acc[i];
  __syncthreads();

  // ---- softmax over j: wave wv (<4) owns row wv exclusively ----
  // score = 256 - 2*S -> max(score) <-> min(S); w = exp2(CC*(Smin - S))
  if (wv < 4) {
    float s[8];
#pragma unroll
    for (int c = 0; c < 8; ++c) s[c] = alg[(wv << 9) + (c << 6) + lane];
    float mn = s[0];
#pragma unroll
    for (int c = 1; c < 8; ++c) mn = fminf(mn, s[c]);
#pragma unroll
    for (int m = 1; m < 64; m <<= 1) mn = fminf(mn, __shfl_xor(mn, m, 64));

    const float CC = 2.8853900817779268f;  // 2*log2(e)
    float p[8];
    float sum = 0.f;
#pragma unroll
    for (int c = 0; c < 8; ++c) { p[c] = fast_exp2(CC * (mn - s[c])); sum += p[c]; }
#pragma unroll
    for (int m = 1; m < 64; m <<= 1) sum += __shfl_xor(sum, m, 64);
    const float inv = fast_rcp(sum);
#pragma unroll
    for (int c = 0; c < 8; ++c) alg[(wv << 9) + (c << 6) + lane] = p[c] * inv;
  }
  __syncthreads();

  // ---- alignment_t write: out2[b][j][i0..i0+3], one float4 per thread ----
  {
    const int j = t;  // 0..511
    float4 av = make_float4(alg[j], alg[512 + j], alg[1024 + j], alg[1536 + j]);
    *(float4*)(out2 + (size_t)(bb * TV + j) * TQ + i0) = av;
  }

  // ---- context: thread t owns (feature f, row-pair rp) ----
  const int f  = t & 255;
  const int rp = t >> 8;          // 0 or 1 -> rows 2rp, 2rp+1
  float c0 = 0.f, c1 = 0.f;
  const float* vb = value + (size_t)bb * TV * DD;
  const float* a0p = &alg[((rp << 1) + 0) << 9];
  const float* a1p = &alg[((rp << 1) + 1) << 9];
#pragma unroll 2
  for (int j = 0; j < TV; j += 4) {
    float v0 = vb[(size_t)(j + 0) * DD + f];
    float v1 = vb[(size_t)(j + 1) * DD + f];
    float v2 = vb[(size_t)(j + 2) * DD + f];
    float v3 = vb[(size_t)(j + 3) * DD + f];
    float4 a0 = *(const float4*)&a0p[j];
    float4 a1 = *(const float4*)&a1p[j];
    c0 += a0.x * v0 + a0.y * v1 + a0.z * v2 + a0.w * v3;
    c1 += a1.x * v0 + a1.y * v1 + a1.z * v2 + a1.w * v3;
  }

  // ---- context-concat output: [ctx | query] per row ----
  const int r0 = (rp << 1), r1 = r0 + 1;
  const float* qg = query + (size_t)(bb * TQ + i0) * DD;
  float* o = out1 + (size_t)(bb * TQ + i0) * (2 * DD);
  o[r0 * 512 + f] = c0; o[r0 * 512 + 256 + f] = qg[r0 * DD + f];
  o[r1 * 512 + f] = c1; o[r1 * 512 + 256 + f] = qg[r1 * DD + f];
}

// ---------------------------------------------------------------------------
extern "C" void kernel_launch(void* const* d_in, const int* in_sizes, int n_in,
                              void* d_out, int out_size, void* d_ws, size_t ws_size,
                              hipStream_t stream) {
  const float* query = (const float*)d_in[0];  // [8,256,256]
  const float* value = (const float*)d_in[1];  // [8,512,256]
  const float* W1    = (const float*)d_in[2];  // [256,256]
  const float* b1    = (const float*)d_in[3];  // [256]
  const float* W2    = (const float*)d_in[4];  // [256,256]
  const float* b2    = (const float*)d_in[5];  // [256]

  float* out1 = (float*)d_out;                     // context concat [8,256,512]
  float* out2 = out1 + (size_t)B_ * TQ * 2 * DD;   // alignment_t   [8,512,256]

  float* qp = (float*)d_ws;                        // Eq: 2048*256 floats
  float* vp = qp + (size_t)B_ * TQ * DD;           // Ev: 4096*256 floats

  const float SC = 2.8853900817779268f;  // 2*log2(e): exp(2x) = exp2(SC*x)

  proj_fused<<<dim3(96, 4), 256, 0, stream>>>(query, value, W1, b1, W2, b2, qp, vp, SC);
  attn_kernel<<<dim3(B_ * (TQ / 4)), 512, 0, stream>>>(qp, vp, value, query, out1, out2);
}

// Round 9
// 139.079 us; speedup vs baseline: 1.0738x; 1.0738x over previous
//
#include <hip/hip_runtime.h>

#define B_  8
#define TQ  256
#define TV  512
#define DD  256

__device__ __forceinline__ float fast_exp2(float x) {
#if __has_builtin(__builtin_amdgcn_exp2f)
  return __builtin_amdgcn_exp2f(x);
#else
  return __exp2f(x);
#endif
}
__device__ __forceinline__ float fast_rcp(float x) {
#if __has_builtin(__builtin_amdgcn_rcpf)
  return __builtin_amdgcn_rcpf(x);
#else
  return 1.0f / x;
#endif
}

// ---------------------------------------------------------------------------
// Fused projections with EXP epilogue (identical to round 8 — validated):
//   Eq = exp2(SC*(query@W1 + b1)),  Ev = exp2(SC*(value@W2 + b2))
// ---------------------------------------------------------------------------
__global__ __launch_bounds__(256) void proj_fused(
    const float* __restrict__ query, const float* __restrict__ value,
    const float* __restrict__ W1, const float* __restrict__ b1,
    const float* __restrict__ W2, const float* __restrict__ b2,
    float* __restrict__ qp, float* __restrict__ vp, float scale) {
  __shared__ float As[2][32][64];  // [p][k][m ^ sw(k)]
  __shared__ float Bs[2][32][64];  // [p][k][n]
  const int t  = threadIdx.x;
  const int rt = blockIdx.x;
  const int bn = blockIdx.y << 6;

  const float* A; const float* W; const float* bias; float* out; int row0;
  if (rt < 32) { row0 = rt << 6;        A = query; W = W1; bias = b1; out = qp; }
  else         { row0 = (rt - 32) << 6; A = value; W = W2; bias = b2; out = vp; }

  const int tx = t & 15, ty = t >> 4;
  const int aar = t >> 3, aac = (t & 7) << 2;
  const int bbr = t >> 4, bbc = (t & 15) << 2;

  float4 ra[2], rb[2];
#pragma unroll
  for (int it = 0; it < 2; ++it) {
    ra[it] = *(const float4*)(A + (size_t)(row0 + (it << 5) + aar) * DD + aac);
    rb[it] = *(const float4*)(W + (size_t)((it << 4) + bbr) * DD + bn + bbc);
  }
#pragma unroll
  for (int it = 0; it < 2; ++it) {
    const int m = (it << 5) + aar;
#pragma unroll
    for (int c = 0; c < 4; ++c) {
      const int k = aac + c;
      As[0][k][m ^ (((k >> 2) & 7) << 2)] = (&ra[it].x)[c];
    }
    *(float4*)&Bs[0][(it << 4) + bbr][bbc] = rb[it];
  }
  __syncthreads();

  float acc[4][4] = {{0.f,0.f,0.f,0.f},{0.f,0.f,0.f,0.f},
                     {0.f,0.f,0.f,0.f},{0.f,0.f,0.f,0.f}};
  int p = 0;

  for (int k0 = 0; k0 < 256; k0 += 32) {
    const bool more = (k0 + 32) < 256;
    if (more) {
#pragma unroll
      for (int it = 0; it < 2; ++it) {
        ra[it] = *(const float4*)(A + (size_t)(row0 + (it << 5) + aar) * DD + k0 + 32 + aac);
        rb[it] = *(const float4*)(W + (size_t)(k0 + 32 + (it << 4) + bbr) * DD + bn + bbc);
      }
    }
#pragma unroll
    for (int k = 0; k < 32; ++k) {
      float4 aq = *(const float4*)&As[p][k][(ty << 2) ^ (((k >> 2) & 7) << 2)];
      float4 bq = *(const float4*)&Bs[p][k][tx << 2];
      acc[0][0] = fmaf(aq.x, bq.x, acc[0][0]); acc[0][1] = fmaf(aq.x, bq.y, acc[0][1]);
      acc[0][2] = fmaf(aq.x, bq.z, acc[0][2]); acc[0][3] = fmaf(aq.x, bq.w, acc[0][3]);
      acc[1][0] = fmaf(aq.y, bq.x, acc[1][0]); acc[1][1] = fmaf(aq.y, bq.y, acc[1][1]);
      acc[1][2] = fmaf(aq.y, bq.z, acc[1][2]); acc[1][3] = fmaf(aq.y, bq.w, acc[1][3]);
      acc[2][0] = fmaf(aq.z, bq.x, acc[2][0]); acc[2][1] = fmaf(aq.z, bq.y, acc[2][1]);
      acc[2][2] = fmaf(aq.z, bq.z, acc[2][2]); acc[2][3] = fmaf(aq.z, bq.w, acc[2][3]);
      acc[3][0] = fmaf(aq.w, bq.x, acc[3][0]); acc[3][1] = fmaf(aq.w, bq.y, acc[3][1]);
      acc[3][2] = fmaf(aq.w, bq.z, acc[3][2]); acc[3][3] = fmaf(aq.w, bq.w, acc[3][3]);
    }
    if (more) {
      const int q = p ^ 1;
#pragma unroll
      for (int it = 0; it < 2; ++it) {
        const int m = (it << 5) + aar;
#pragma unroll
        for (int c = 0; c < 4; ++c) {
          const int k = aac + c;
          As[q][k][m ^ (((k >> 2) & 7) << 2)] = (&ra[it].x)[c];
        }
        *(float4*)&Bs[q][(it << 4) + bbr][bbc] = rb[it];
      }
      __syncthreads();
      p = q;
    }
  }

  float4 bvv = *(const float4*)&bias[bn + (tx << 2)];
#pragma unroll
  for (int r = 0; r < 4; ++r) {
    float4 o;
    o.x = fast_exp2(scale * (acc[r][0] + bvv.x));
    o.y = fast_exp2(scale * (acc[r][1] + bvv.y));
    o.z = fast_exp2(scale * (acc[r][2] + bvv.z));
    o.w = fast_exp2(scale * (acc[r][3] + bvv.w));
    *(float4*)(out + (size_t)(row0 + (ty << 2) + r) * DD + bn + (tx << 2)) = o;
  }
}

// ---------------------------------------------------------------------------
// Fused score + softmax + context + concat + transposed alignment.
// 512 blocks x 512 threads (8 waves). LDS = 2 x 512 x 20 x 4 = 81920 B
// -> 2 blocks/CU (exactly 160 KiB). lane = j (fixed); acc in VGPRs.
// d processed in 16 sub-chunks of 16 d, DOUBLE-BUFFERED (stride 20 words:
// b128-aligned, <=2-way bank phase on reads = free). Per sub-chunk:
// issue 4 staging float4 loads FIRST, compute current buffer (~550 cy,
// covers L2 latency), then write the prefetched regs and barrier once.
// q reads are wave-uniform -> scalar-load path, zero q LDS traffic.
// Math (Eq,Ev; x = Eq*Ev = exp(2(q+v))), quad-rcp:
//   sum 1/(1+x) over 4 elems = one rcp via pair/pair combine.
// score = 256 - 2*S;  softmax via min-S trick.
// ---------------------------------------------------------------------------
__global__ __launch_bounds__(512, 4) void attn_kernel(
    const float* __restrict__ qp, const float* __restrict__ vp,
    const float* __restrict__ value, const float* __restrict__ query,
    float* __restrict__ out1, float* __restrict__ out2) {
  __shared__ float vs2[2][512 * 20];  // 81920 B; [0] aliased as alg after loop
  float* alg = &vs2[0][0];            // alg[i*512 + j]

  const int t    = threadIdx.x;
  const int lane = t & 63;
  const int wv   = t >> 6;        // 0..7
  const int bb   = blockIdx.x & 7;          // batch -> XCD locality
  const int i0   = (blockIdx.x >> 3) << 2;  // first q-row of this block
  const int jrow = (wv << 6) + lane;        // this lane's j (fixed)

  const float* vpb = vp + (size_t)bb * TV * DD;
  const float* qb  = qp + (size_t)(bb * TQ + i0) * DD;  // wave-uniform reads

  const int sj = t >> 2;          // staging row base 0..127
  const int sc = (t & 3) << 2;    // staging col 0/4/8/12 (64B per lane-quad)

  float acc[4] = {0.f, 0.f, 0.f, 0.f};

  // stage sub-chunk 0 into buffer 0
#pragma unroll
  for (int k = 0; k < 4; ++k) {
    const int j = (k << 7) + sj;
    float4 x = *(const float4*)(vpb + (size_t)j * DD + sc);
    *(float4*)&vs2[0][j * 20 + sc] = x;
  }
  __syncthreads();

#pragma unroll 1
  for (int s = 0; s < 16; ++s) {
    float4 r0, r1, r2, r3;
    if (s < 15) {  // issue next sub-chunk loads BEFORE compute
      const int dn = (s + 1) << 4;
      r0 = *(const float4*)(vpb + (size_t)(sj)       * DD + dn + sc);
      r1 = *(const float4*)(vpb + (size_t)(128 + sj) * DD + dn + sc);
      r2 = *(const float4*)(vpb + (size_t)(256 + sj) * DD + dn + sc);
      r3 = *(const float4*)(vpb + (size_t)(384 + sj) * DD + dn + sc);
    }

    const float* vrow = &vs2[s & 1][jrow * 20];
    const int dbase = s << 4;
#pragma unroll
    for (int d4 = 0; d4 < 4; ++d4) {
      float4 v4 = *(const float4*)&vrow[d4 << 2];
#pragma unroll
      for (int i = 0; i < 4; ++i) {
        float4 q4 = *(const float4*)(qb + i * DD + dbase + (d4 << 2));
        float a = q4.x * v4.x, b = q4.y * v4.y;
        float c = q4.z * v4.z, d = q4.w * v4.w;
        float sab = a + b,  scd = c + d;
        float Q1 = fmaf(a, b, sab + 1.f);   // (1+a)(1+b)
        float Q2 = fmaf(c, d, scd + 1.f);   // (1+c)(1+d)
        float P1 = sab + 2.f, P2 = scd + 2.f;
        float N  = fmaf(P2, Q1, P1 * Q2);
        acc[i] = fmaf(N, fast_rcp(Q1 * Q2), acc[i]);
      }
    }

    if (s < 15) {  // write prefetched regs into the other buffer
      const int nb = (s + 1) & 1;
      *(float4*)&vs2[nb][(sj)       * 20 + sc] = r0;
      *(float4*)&vs2[nb][(128 + sj) * 20 + sc] = r1;
      *(float4*)&vs2[nb][(256 + sj) * 20 + sc] = r2;
      *(float4*)&vs2[nb][(384 + sj) * 20 + sc] = r3;
    }
    __syncthreads();  // one barrier per sub-chunk
  }

  // ---- scores -> alg (aliases vs2[0]; loop fully fenced) ----
#pragma unroll
  for (int i = 0; i < 4; ++i) alg[(i << 9) + jrow] = acc[i];
  __syncthreads();

  // ---- softmax over j: wave wv (<4) owns row wv exclusively ----
  // score = 256 - 2*S -> max(score) <-> min(S); w = exp2(CC*(Smin - S))
  if (wv < 4) {
    float s[8];
#pragma unroll
    for (int c = 0; c < 8; ++c) s[c] = alg[(wv << 9) + (c << 6) + lane];
    float mn = s[0];
#pragma unroll
    for (int c = 1; c < 8; ++c) mn = fminf(mn, s[c]);
#pragma unroll
    for (int m = 1; m < 64; m <<= 1) mn = fminf(mn, __shfl_xor(mn, m, 64));

    const float CC = 2.8853900817779268f;  // 2*log2(e)
    float p[8];
    float sum = 0.f;
#pragma unroll
    for (int c = 0; c < 8; ++c) { p[c] = fast_exp2(CC * (mn - s[c])); sum += p[c]; }
#pragma unroll
    for (int m = 1; m < 64; m <<= 1) sum += __shfl_xor(sum, m, 64);
    const float inv = fast_rcp(sum);
#pragma unroll
    for (int c = 0; c < 8; ++c) alg[(wv << 9) + (c << 6) + lane] = p[c] * inv;
  }
  __syncthreads();

  // ---- alignment_t write: out2[b][j][i0..i0+3], one float4 per thread ----
  {
    const int j = t;  // 0..511
    float4 av = make_float4(alg[j], alg[512 + j], alg[1024 + j], alg[1536 + j]);
    *(float4*)(out2 + (size_t)(bb * TV + j) * TQ + i0) = av;
  }

  // ---- context: thread t owns (feature f, row-pair rp) ----
  const int f  = t & 255;
  const int rp = t >> 8;          // 0 or 1 -> rows 2rp, 2rp+1
  float c0 = 0.f, c1 = 0.f;
  const float* vb = value + (size_t)bb * TV * DD;
  const float* a0p = &alg[((rp << 1) + 0) << 9];
  const float* a1p = &alg[((rp << 1) + 1) << 9];
#pragma unroll 4
  for (int j = 0; j < TV; j += 4) {
    float v0 = vb[(size_t)(j + 0) * DD + f];
    float v1 = vb[(size_t)(j + 1) * DD + f];
    float v2 = vb[(size_t)(j + 2) * DD + f];
    float v3 = vb[(size_t)(j + 3) * DD + f];
    float4 a0 = *(const float4*)&a0p[j];
    float4 a1 = *(const float4*)&a1p[j];
    c0 += a0.x * v0 + a0.y * v1 + a0.z * v2 + a0.w * v3;
    c1 += a1.x * v0 + a1.y * v1 + a1.z * v2 + a1.w * v3;
  }

  // ---- context-concat output: [ctx | query] per row ----
  const int r0_ = (rp << 1), r1_ = r0_ + 1;
  const float* qg = query + (size_t)(bb * TQ + i0) * DD;
  float* o = out1 + (size_t)(bb * TQ + i0) * (2 * DD);
  o[r0_ * 512 + f] = c0; o[r0_ * 512 + 256 + f] = qg[r0_ * DD + f];
  o[r1_ * 512 + f] = c1; o[r1_ * 512 + 256 + f] = qg[r1_ * DD + f];
}

// ---------------------------------------------------------------------------
extern "C" void kernel_launch(void* const* d_in, const int* in_sizes, int n_in,
                              void* d_out, int out_size, void* d_ws, size_t ws_size,
                              hipStream_t stream) {
  const float* query = (const float*)d_in[0];  // [8,256,256]
  const float* value = (const float*)d_in[1];  // [8,512,256]
  const float* W1    = (const float*)d_in[2];  // [256,256]
  const float* b1    = (const float*)d_in[3];  // [256]
  const float* W2    = (const float*)d_in[4];  // [256,256]
  const float* b2    = (const float*)d_in[5];  // [256]

  float* out1 = (float*)d_out;                     // context concat [8,256,512]
  float* out2 = out1 + (size_t)B_ * TQ * 2 * DD;   // alignment_t   [8,512,256]

  float* qp = (float*)d_ws;                        // Eq: 2048*256 floats
  float* vp = qp + (size_t)B_ * TQ * DD;           // Ev: 4096*256 floats

  const float SC = 2.8853900817779268f;  // 2*log2(e): exp(2x) = exp2(SC*x)

  proj_fused<<<dim3(96, 4), 256, 0, stream>>>(query, value, W1, b1, W2, b2, qp, vp, SC);
  attn_kernel<<<dim3(B_ * (TQ / 4)), 512, 0, stream>>>(qp, vp, value, query, out1, out2);
}